// Round 9
// baseline (680.118 us; speedup 1.0000x reference)
//
#include <hip/hip_runtime.h>
#include <hip/hip_bf16.h>

#define AST_DIM 256
#define NR_AST 500000
#define NR_CFG 100000
#define NR_MAP 400000
#define NR_UNMAP (NR_AST - NR_MAP)   // 100000
#define NMIX (NR_MAP / 32)           // 12500 mixer blocks (BM=32)
#define NTOT 13542                   // 12500 mixer + 1041 copy, 13-interleaved
#define NCOPY 1041
#define COPY_STRIDE (NCOPY * 8)      // wave-level tasks stride

typedef short short8 __attribute__((ext_vector_type(8)));
typedef float f32x4 __attribute__((ext_vector_type(4)));
typedef unsigned long long u64;
typedef unsigned int u32;

__device__ __forceinline__ unsigned short f2bf(float f) {
    u32 u = __float_as_uint(f);
    u += 0x7FFFu + ((u >> 16) & 1u);   // RNE
    return (unsigned short)(u >> 16);
}
__device__ __forceinline__ float bf2f(unsigned short s) {
    return __uint_as_float(((u32)s) << 16);
}
__device__ __forceinline__ u64 pack4(f32x4 v) {
    __hip_bfloat162 lo = __float22bfloat162_rn(float2{v.x, v.y});  // v_cvt_pk_bf16_f32
    __hip_bfloat162 hi = __float22bfloat162_rn(float2{v.z, v.w});
    return (u64)(*(u32*)&lo) | ((u64)(*(u32*)&hi) << 32);
}
__device__ __forceinline__ float fast_tanh(float x) {
    return 1.f - 2.f * __builtin_amdgcn_rcpf(__expf(2.f * x) + 1.f);
}
__device__ __forceinline__ float fast_sigmoid(float x) {
    return __builtin_amdgcn_rcpf(1.f + __expf(-x));
}
// async global->LDS DMA, 16B/lane: LDS dest = wave-uniform base + lane*16 (linear);
// global src is per-lane (enables source-side swizzling).
__device__ __forceinline__ void dma16(const void* g, void* l) {
    __builtin_amdgcn_global_load_lds((const __attribute__((address_space(1))) u32*)g,
                                     (__attribute__((address_space(3))) u32*)l, 16, 0, 0);
}

// W_update / W_gate (f32, [K][N]) -> bf16 transposed [N][K].
__global__ void convert_w(const float* __restrict__ Wu, const float* __restrict__ Wg,
                          unsigned short* __restrict__ wt) {
    int idx = blockIdx.x * 256 + threadIdx.x;
    if (idx >= 3 * 65536) return;
    int m = idx >> 16;
    int r = idx & 65535;
    int n = r >> 8;
    int k = r & 255;
    float v;
    if (m == 0)      v = Wu[k * 256 + n];
    else if (m == 1) v = Wg[k * 256 + n];
    else             v = Wg[(k + 256) * 256 + n];
    wt[idx] = f2bf(v);
}

__global__ void set_mask(const int* __restrict__ keys, unsigned char* __restrict__ mask) {
    int i = blockIdx.x * 256 + threadIdx.x;
    if (i < NR_MAP) mask[keys[i]] = 1;
}

// Build compacted list of UNMAPPED rows (100K) so the copy touches 204MB not 614MB.
__global__ void compact_unmapped(const unsigned char* __restrict__ mask,
                                 int* __restrict__ list, int* __restrict__ counter) {
    int i = blockIdx.x * 256 + threadIdx.x;
    if (i < NR_AST && !mask[i]) {
        int p = atomicAdd(counter, 1);
        list[p] = i;
    }
}

// Fallback copy (ws too small): full masked stream.
__global__ void copy_unmapped(const float* __restrict__ prev,
                              const unsigned char* __restrict__ mask,
                              float* __restrict__ out) {
    const long long total = (long long)NR_AST * 64;
    for (long long i = (long long)blockIdx.x * blockDim.x + threadIdx.x; i < total;
         i += (long long)gridDim.x * blockDim.x) {
        int row = (int)(i >> 6);
        if (!mask[row]) {
            f32x4 v = __builtin_nontemporal_load((const f32x4*)prev + i);
            __builtin_nontemporal_store(v, (f32x4*)out + i);
        }
    }
}

// Pass A: u_all[c] = tanh(cfg[c] @ Wu + bu) for ALL 100K cfg rows (dense stream).
__global__ __launch_bounds__(512, 4) void compute_u(
    const float* __restrict__ cfg, const unsigned short* __restrict__ Wtu,
    const float* __restrict__ bu, unsigned short* __restrict__ u_all) {
    __shared__ __align__(16) unsigned char ctxb[64 * 512];

    const int tid = threadIdx.x;
    const int lane = tid & 63;
    const int wv = tid >> 6;
    const int ln15 = lane & 15;
    const int khi = lane >> 4;
    const int cb = wv * 32;
    const int m0 = blockIdx.x * 64;

#pragma unroll
    for (int i = 0; i < 8; ++i) {
        int r = wv * 8 + i;
        int g = m0 + r;
        if (g >= NR_CFG) g = NR_CFG - 1;
        f32x4 v = *((const f32x4*)(cfg + (size_t)g * AST_DIM) + lane);
        int addr = (r << 9) + ((lane << 3) ^ ((r & 7) << 4));
        *(u64*)(ctxb + addr) = pack4(v);
    }
    __syncthreads();

    const float b0 = bu[cb + ln15], b1 = bu[cb + 16 + ln15];
    f32x4 acc[4][2];
#pragma unroll
    for (int mt = 0; mt < 4; ++mt) {
        acc[mt][0] = f32x4{b0, b0, b0, b0};
        acc[mt][1] = f32x4{b1, b1, b1, b1};
    }
#pragma unroll
    for (int ks = 0; ks < 8; ++ks) {
        short8 a[4], b[2];
#pragma unroll
        for (int mt = 0; mt < 4; ++mt) {
            int row = mt * 16 + ln15;
            int addr = (row << 9) + (((ks << 6) + (khi << 4)) ^ ((row & 7) << 4));
            a[mt] = *(const short8*)(ctxb + addr);
        }
#pragma unroll
        for (int nt = 0; nt < 2; ++nt)
            b[nt] = *(const short8*)(Wtu + (cb + nt * 16 + ln15) * 256 + ks * 32 + khi * 8);
#pragma unroll
        for (int mt = 0; mt < 4; ++mt)
#pragma unroll
            for (int nt = 0; nt < 2; ++nt)
                acc[mt][nt] = __builtin_amdgcn_mfma_f32_16x16x32_bf16(a[mt], b[nt], acc[mt][nt], 0, 0, 0);
    }
#pragma unroll
    for (int mt = 0; mt < 4; ++mt)
#pragma unroll
        for (int rr = 0; rr < 4; ++rr) {
            int row = mt * 16 + khi * 4 + rr;
            int g = m0 + row;
            if (g < NR_CFG) {
#pragma unroll
                for (int nt = 0; nt < 2; ++nt) {
                    int col = cb + nt * 16 + ln15;
                    u_all[(size_t)g * AST_DIM + col] = f2bf(fast_tanh(acc[mt][nt][rr]));
                }
            }
        }
}

// Main fused kernel. Grid of 13542 blocks, 13-interleaved:
//   r = b%13 == 12 -> copy block (streams compacted unmapped rows, fills HBM bubbles)
//   else           -> mixer block (BM=32): gather prev+u, 1 barrier, GEMM2, blend, scatter.
// 32KB LDS + <=64 VGPR -> 4 blocks/CU, ~100% occupancy for latency hiding.
__global__ __launch_bounds__(512, 8) void fused_main(
    const float* __restrict__ prev, const unsigned short* __restrict__ u_all,
    const int* __restrict__ keys, const int* __restrict__ vals,
    const int* __restrict__ list,
    const unsigned short* __restrict__ Wtgt, const unsigned short* __restrict__ Wtgb,
    const float* __restrict__ bg, float* __restrict__ out) {
    __shared__ __align__(16) unsigned char prvb[32 * 512];  // bf16 swizzled prev tile
    __shared__ __align__(16) unsigned char u_st[32 * 512];  // bf16 swizzled u tile

    const int b = blockIdx.x;
    const int q = b / 13;
    const int rmod = b % 13;
    const int tid = threadIdx.x;
    const int lane = tid & 63;
    const int wv = tid >> 6;

    if (rmod == 12) {
        // ---- copy block: wave-per-row over the compacted unmapped list ----
        for (int ci = q * 8 + wv; ci < NR_UNMAP; ci += COPY_STRIDE) {
            int row = list[ci];
            f32x4 v = __builtin_nontemporal_load((const f32x4*)(prev + (size_t)row * AST_DIM) + lane);
            __builtin_nontemporal_store(v, (f32x4*)(out + (size_t)row * AST_DIM) + lane);
        }
        return;
    }
    const int id = q * 12 + rmod;
    if (id >= NMIX) return;

    const int ln15 = lane & 15;
    const int khi = lane >> 4;
    const int ln31 = lane & 31;
    const int cb = wv * 32;
    const int m0 = id * 32;

    const int kv = keys[m0 + ln31];
    const int vv = vals[m0 + ln31];

    // ---- u gathers: async DMA, 2 rows/instr, source-side swizzle ----
#pragma unroll
    for (int i = 0; i < 2; ++i) {
        int r0 = wv * 4 + i * 2;
        int row = r0 + (lane >> 5);
        int vidx = __shfl(vv, row);
        const unsigned short* src = u_all + (size_t)vidx * AST_DIM + ((ln31 ^ (row & 7)) << 3);
        dma16(src, u_st + (r0 << 9));
    }
    // ---- prev gathers: f32x4 -> bf16 pack -> swizzled LDS (DMA flies underneath) ----
#pragma unroll
    for (int i = 0; i < 4; ++i) {
        int r = wv * 4 + i;
        int kidx = __shfl(kv, r);
        f32x4 v = *((const f32x4*)(prev + (size_t)kidx * AST_DIM) + lane);
        int addr = (r << 9) + ((lane << 3) ^ ((r & 7) << 4));
        *(u64*)(prvb + addr) = pack4(v);
    }
    __syncthreads();   // drains DMA + packs; the ONLY barrier

    // ---- GEMM2: z_pre = prev @ Wg_top + u @ Wg_bot + bg ----
    const float b0 = bg[cb + ln15], b1 = bg[cb + 16 + ln15];
    f32x4 acc[2][2];
    acc[0][0] = f32x4{b0, b0, b0, b0};
    acc[0][1] = f32x4{b1, b1, b1, b1};
    acc[1][0] = acc[0][0];
    acc[1][1] = acc[0][1];
#pragma unroll
    for (int ks = 0; ks < 8; ++ks) {
        short8 a[2], bfr[2];
#pragma unroll
        for (int mt = 0; mt < 2; ++mt) {
            int row = mt * 16 + ln15;
            int addr = (row << 9) + (((ks << 6) + (khi << 4)) ^ ((row & 7) << 4));
            a[mt] = *(const short8*)(prvb + addr);
        }
#pragma unroll
        for (int nt = 0; nt < 2; ++nt)
            bfr[nt] = *(const short8*)(Wtgt + (cb + nt * 16 + ln15) * 256 + ks * 32 + khi * 8);
#pragma unroll
        for (int mt = 0; mt < 2; ++mt)
#pragma unroll
            for (int nt = 0; nt < 2; ++nt)
                acc[mt][nt] = __builtin_amdgcn_mfma_f32_16x16x32_bf16(a[mt], bfr[nt], acc[mt][nt], 0, 0, 0);
    }
#pragma unroll
    for (int ks = 0; ks < 8; ++ks) {
        short8 a[2], bfr[2];
#pragma unroll
        for (int mt = 0; mt < 2; ++mt) {
            int row = mt * 16 + ln15;
            int addr = (row << 9) + ((((ks << 2) + khi) ^ (row & 7)) << 4);
            a[mt] = *(const short8*)(u_st + addr);
        }
#pragma unroll
        for (int nt = 0; nt < 2; ++nt)
            bfr[nt] = *(const short8*)(Wtgb + (cb + nt * 16 + ln15) * 256 + ks * 32 + khi * 8);
#pragma unroll
        for (int mt = 0; mt < 2; ++mt)
#pragma unroll
            for (int nt = 0; nt < 2; ++nt)
                acc[mt][nt] = __builtin_amdgcn_mfma_f32_16x16x32_bf16(a[mt], bfr[nt], acc[mt][nt], 0, 0, 0);
    }

    // ---- epilogue: z = sigmoid, blend, scatter store ----
#pragma unroll
    for (int mt = 0; mt < 2; ++mt)
#pragma unroll
        for (int rr = 0; rr < 4; ++rr) {
            int row = mt * 16 + khi * 4 + rr;
            int key = __shfl(kv, row);
            float* orow = out + (size_t)key * AST_DIM;
#pragma unroll
            for (int nt = 0; nt < 2; ++nt) {
                int col = cb + nt * 16 + ln15;
                float z = fast_sigmoid(acc[mt][nt][rr]);
                float pf = bf2f(*(const unsigned short*)(prvb + (row << 9) + ((col << 1) ^ ((row & 7) << 4))));
                float uv = bf2f(*(const unsigned short*)(u_st + (row << 9) +
                                ((((col >> 3) ^ (row & 7)) << 4) + ((col & 7) << 1))));
                __builtin_nontemporal_store(fmaf(z, pf - uv, uv), orow + col);  // z*prev+(1-z)*u
            }
        }
}

// Fallback (ws too small): round-1-style fused kernel, known-good.
__global__ __launch_bounds__(512, 4) void mixer_fused(
    const float* __restrict__ prev, const float* __restrict__ cfg,
    const int* __restrict__ keys, const int* __restrict__ vals,
    const unsigned short* __restrict__ Wtu, const unsigned short* __restrict__ Wtgt,
    const unsigned short* __restrict__ Wtgb, const float* __restrict__ bu,
    const float* __restrict__ bg, float* __restrict__ out) {
    __shared__ __align__(16) unsigned char ctx_lds[64 * 512];
    __shared__ __align__(16) unsigned char prv_lds[64 * 512];

    const int tid = threadIdx.x;
    const int lane = tid & 63;
    const int wave = tid >> 6;
    const int ln15 = lane & 15;
    const int khi = lane >> 4;
    const int cb = wave * 32;
    const int m0 = blockIdx.x * 64;

    const int kv = keys[m0 + lane];
    const int vv = vals[m0 + lane];

#pragma unroll 4
    for (int i = 0; i < 8; ++i) {
        int r = i * 8 + wave;
        f32x4 cv = *((const f32x4*)(cfg + (size_t)__shfl(vv, r) * AST_DIM) + lane);
        f32x4 pv = *((const f32x4*)(prev + (size_t)__shfl(kv, r) * AST_DIM) + lane);
        int addr = (r << 9) + ((lane << 3) ^ ((r & 7) << 4));
        *(u64*)(ctx_lds + addr) = pack4(cv);
        *(u64*)(prv_lds + addr) = pack4(pv);
    }
    __syncthreads();

    f32x4 acc[4][2];
    {
        float b0 = bu[cb + ln15], b1 = bu[cb + 16 + ln15];
        for (int mt = 0; mt < 4; ++mt) {
            acc[mt][0] = f32x4{b0, b0, b0, b0};
            acc[mt][1] = f32x4{b1, b1, b1, b1};
        }
    }
#pragma unroll
    for (int ks = 0; ks < 8; ++ks) {
        short8 a[4], b[2];
        for (int mt = 0; mt < 4; ++mt) {
            int row = mt * 16 + ln15;
            int addr = (row << 9) + (((ks << 6) + (khi << 4)) ^ ((row & 7) << 4));
            a[mt] = *(const short8*)(ctx_lds + addr);
        }
        for (int nt = 0; nt < 2; ++nt)
            b[nt] = *(const short8*)(Wtu + (cb + nt * 16 + ln15) * 256 + ks * 32 + khi * 8);
        for (int mt = 0; mt < 4; ++mt)
            for (int nt = 0; nt < 2; ++nt)
                acc[mt][nt] = __builtin_amdgcn_mfma_f32_16x16x32_bf16(a[mt], b[nt], acc[mt][nt], 0, 0, 0);
    }
    __syncthreads();
#pragma unroll
    for (int mt = 0; mt < 4; ++mt)
        for (int rr = 0; rr < 4; ++rr) {
            int row = mt * 16 + khi * 4 + rr;
            for (int nt = 0; nt < 2; ++nt) {
                int col = cb + nt * 16 + ln15;
                int addr = (row << 9) + ((col << 1) ^ ((row & 7) << 4));
                *(unsigned short*)(ctx_lds + addr) = f2bf(fast_tanh(acc[mt][nt][rr]));
            }
        }
    __syncthreads();
    {
        float b0 = bg[cb + ln15], b1 = bg[cb + 16 + ln15];
        for (int mt = 0; mt < 4; ++mt) {
            acc[mt][0] = f32x4{b0, b0, b0, b0};
            acc[mt][1] = f32x4{b1, b1, b1, b1};
        }
    }
#pragma unroll
    for (int ks = 0; ks < 8; ++ks) {
        short8 a[4], b[2];
        for (int mt = 0; mt < 4; ++mt) {
            int row = mt * 16 + ln15;
            int addr = (row << 9) + (((ks << 6) + (khi << 4)) ^ ((row & 7) << 4));
            a[mt] = *(const short8*)(prv_lds + addr);
        }
        for (int nt = 0; nt < 2; ++nt)
            b[nt] = *(const short8*)(Wtgt + (cb + nt * 16 + ln15) * 256 + ks * 32 + khi * 8);
        for (int mt = 0; mt < 4; ++mt)
            for (int nt = 0; nt < 2; ++nt)
                acc[mt][nt] = __builtin_amdgcn_mfma_f32_16x16x32_bf16(a[mt], b[nt], acc[mt][nt], 0, 0, 0);
    }
#pragma unroll
    for (int ks = 0; ks < 8; ++ks) {
        short8 a[4], b[2];
        for (int mt = 0; mt < 4; ++mt) {
            int row = mt * 16 + ln15;
            int addr = (row << 9) + (((ks << 6) + (khi << 4)) ^ ((row & 7) << 4));
            a[mt] = *(const short8*)(ctx_lds + addr);
        }
        for (int nt = 0; nt < 2; ++nt)
            b[nt] = *(const short8*)(Wtgb + (cb + nt * 16 + ln15) * 256 + ks * 32 + khi * 8);
        for (int mt = 0; mt < 4; ++mt)
            for (int nt = 0; nt < 2; ++nt)
                acc[mt][nt] = __builtin_amdgcn_mfma_f32_16x16x32_bf16(a[mt], b[nt], acc[mt][nt], 0, 0, 0);
    }
#pragma unroll
    for (int mt = 0; mt < 4; ++mt)
        for (int rr = 0; rr < 4; ++rr) {
            int row = mt * 16 + khi * 4 + rr;
            int key = __shfl(kv, row);
            float* orow = out + (size_t)key * AST_DIM;
            for (int nt = 0; nt < 2; ++nt) {
                int col = cb + nt * 16 + ln15;
                int ad = (row << 9) + ((col << 1) ^ ((row & 7) << 4));
                float z = fast_sigmoid(acc[mt][nt][rr]);
                float pf = bf2f(*(const unsigned short*)(prv_lds + ad));
                float uv = bf2f(*(const unsigned short*)(ctx_lds + ad));
                orow[col] = fmaf(z, pf - uv, uv);
            }
        }
}

extern "C" void kernel_launch(void* const* d_in, const int* in_sizes, int n_in,
                              void* d_out, int out_size, void* d_ws, size_t ws_size,
                              hipStream_t stream) {
    const float* prev = (const float*)d_in[0];
    const float* cfg = (const float*)d_in[1];
    const int* keys = (const int*)d_in[2];
    const int* vals = (const int*)d_in[3];
    const float* Wu = (const float*)d_in[4];
    const float* bu = (const float*)d_in[5];
    const float* Wg = (const float*)d_in[6];
    const float* bg = (const float*)d_in[7];
    float* out = (float*)d_out;

    // ws: [0,384K) wt | [384K,884K) mask | [917504] counter | [983040,+400K) list | [2MB,+51.2MB) u_all
    unsigned short* wt = (unsigned short*)d_ws;
    unsigned char* mask = (unsigned char*)d_ws + 3 * 65536 * 2;
    int* counter = (int*)((char*)d_ws + 917504);
    int* list = (int*)((char*)d_ws + 983040);
    unsigned short* u_all = (unsigned short*)((char*)d_ws + (2u << 20));
    const size_t ws_needed = (size_t)(2u << 20) + (size_t)NR_CFG * AST_DIM * 2;  // ~53.4 MB

    // zero mask + counter region
    (void)hipMemsetAsync(mask, 0, 917504 + 4 - 3 * 65536 * 2, stream);
    convert_w<<<768, 256, 0, stream>>>(Wu, Wg, wt);
    set_mask<<<(NR_MAP + 255) / 256, 256, 0, stream>>>(keys, mask);
    if (ws_size >= ws_needed) {
        compact_unmapped<<<(NR_AST + 255) / 256, 256, 0, stream>>>(mask, list, counter);
        compute_u<<<(NR_CFG + 63) / 64, 512, 0, stream>>>(cfg, wt, bu, u_all);
        fused_main<<<NTOT, 512, 0, stream>>>(prev, u_all, keys, vals, list,
                                             wt + 65536, wt + 2 * 65536, bg, out);
    } else {
        copy_unmapped<<<2048, 256, 0, stream>>>(prev, mask, out);
        mixer_fused<<<NR_MAP / 64, 512, 0, stream>>>(prev, cfg, keys, vals, wt, wt + 65536,
                                                     wt + 2 * 65536, bu, bg, out);
    }
}

// Round 10
// 455.719 us; speedup vs baseline: 1.4924x; 1.4924x over previous
//
#include <hip/hip_runtime.h>
#include <hip/hip_bf16.h>

#define AST_DIM 256
#define NR_AST 500000
#define NR_CFG 100000
#define NR_MAP 400000
#define NBLK_MAIN ((NR_AST + 63) / 64)   // 7813

typedef short short8 __attribute__((ext_vector_type(8)));
typedef float f32x4 __attribute__((ext_vector_type(4)));
typedef unsigned long long u64;
typedef unsigned int u32;

__device__ __forceinline__ unsigned short f2bf(float f) {
    u32 u = __float_as_uint(f);
    u += 0x7FFFu + ((u >> 16) & 1u);   // RNE
    return (unsigned short)(u >> 16);
}
__device__ __forceinline__ float bf2f(unsigned short s) {
    return __uint_as_float(((u32)s) << 16);
}
__device__ __forceinline__ u64 pack4(f32x4 v) {
    __hip_bfloat162 lo = __float22bfloat162_rn(float2{v.x, v.y});  // v_cvt_pk_bf16_f32
    __hip_bfloat162 hi = __float22bfloat162_rn(float2{v.z, v.w});
    return (u64)(*(u32*)&lo) | ((u64)(*(u32*)&hi) << 32);
}
__device__ __forceinline__ float fast_tanh(float x) {
    return 1.f - 2.f * __builtin_amdgcn_rcpf(__expf(2.f * x) + 1.f);
}
__device__ __forceinline__ float fast_sigmoid(float x) {
    return __builtin_amdgcn_rcpf(1.f + __expf(-x));
}
// async global->LDS DMA, 16B/lane: LDS dest = wave-uniform base + lane*16 (linear);
// global src is per-lane (enables source-side swizzling).
__device__ __forceinline__ void dma16(const void* g, void* l) {
    __builtin_amdgcn_global_load_lds((const __attribute__((address_space(1))) u32*)g,
                                     (__attribute__((address_space(3))) u32*)l, 16, 0, 0);
}

// W_update / W_gate (f32, [K][N]) -> bf16 transposed [N][K].
__global__ void convert_w(const float* __restrict__ Wu, const float* __restrict__ Wg,
                          unsigned short* __restrict__ wt) {
    int idx = blockIdx.x * 256 + threadIdx.x;
    if (idx >= 3 * 65536) return;
    int m = idx >> 16;
    int r = idx & 65535;
    int n = r >> 8;
    int k = r & 255;
    float v;
    if (m == 0)      v = Wu[k * 256 + n];
    else if (m == 1) v = Wg[k * 256 + n];
    else             v = Wg[(k + 256) * 256 + n];
    wt[idx] = f2bf(v);
}

// Invert the permutation: val_of_row[keys[m]] = vals[m]; elsewhere -1 (preset).
__global__ void build_vor(const int* __restrict__ keys, const int* __restrict__ vals,
                          int* __restrict__ vor) {
    int i = blockIdx.x * 256 + threadIdx.x;
    if (i < NR_MAP) vor[keys[i]] = vals[i];
}

// Pass A: u_all[c] = tanh(cfg[c] @ Wu + bu) for ALL 100K cfg rows (dense stream).
__global__ __launch_bounds__(512, 4) void compute_u(
    const float* __restrict__ cfg, const unsigned short* __restrict__ Wtu,
    const float* __restrict__ bu, unsigned short* __restrict__ u_all) {
    __shared__ __align__(16) unsigned char ctxb[64 * 512];

    const int tid = threadIdx.x;
    const int lane = tid & 63;
    const int wv = tid >> 6;
    const int ln15 = lane & 15;
    const int khi = lane >> 4;
    const int cb = wv * 32;
    const int m0 = blockIdx.x * 64;

#pragma unroll
    for (int i = 0; i < 8; ++i) {
        int r = wv * 8 + i;
        int g = m0 + r;
        if (g >= NR_CFG) g = NR_CFG - 1;
        f32x4 v = *((const f32x4*)(cfg + (size_t)g * AST_DIM) + lane);
        int addr = (r << 9) + ((lane << 3) ^ ((r & 7) << 4));
        *(u64*)(ctxb + addr) = pack4(v);
    }
    __syncthreads();

    const float b0 = bu[cb + ln15], b1 = bu[cb + 16 + ln15];
    f32x4 acc[4][2];
#pragma unroll
    for (int mt = 0; mt < 4; ++mt) {
        acc[mt][0] = f32x4{b0, b0, b0, b0};
        acc[mt][1] = f32x4{b1, b1, b1, b1};
    }
#pragma unroll
    for (int ks = 0; ks < 8; ++ks) {
        short8 a[4], b[2];
#pragma unroll
        for (int mt = 0; mt < 4; ++mt) {
            int row = mt * 16 + ln15;
            int addr = (row << 9) + (((ks << 6) + (khi << 4)) ^ ((row & 7) << 4));
            a[mt] = *(const short8*)(ctxb + addr);
        }
#pragma unroll
        for (int nt = 0; nt < 2; ++nt)
            b[nt] = *(const short8*)(Wtu + (cb + nt * 16 + ln15) * 256 + ks * 32 + khi * 8);
#pragma unroll
        for (int mt = 0; mt < 4; ++mt)
#pragma unroll
            for (int nt = 0; nt < 2; ++nt)
                acc[mt][nt] = __builtin_amdgcn_mfma_f32_16x16x32_bf16(a[mt], b[nt], acc[mt][nt], 0, 0, 0);
    }
#pragma unroll
    for (int mt = 0; mt < 4; ++mt)
#pragma unroll
        for (int rr = 0; rr < 4; ++rr) {
            int row = mt * 16 + khi * 4 + rr;
            int g = m0 + row;
            if (g < NR_CFG) {
#pragma unroll
                for (int nt = 0; nt < 2; ++nt) {
                    int col = cb + nt * 16 + ln15;
                    u_all[(size_t)g * AST_DIM + col] = f2bf(fast_tanh(acc[mt][nt][rr]));
                }
            }
        }
}

// Main: iterate OUTPUT rows in order (prev read + out write both sequential);
// only u_all rows are gathered (51MB, L3-resident). Unmapped rows are copied
// f32-exact inline during staging; MFMA computes garbage for them (store
// predicated off). 7813 blocks x 512 thr, 64 rows/block, 64KB LDS -> 2 blk/CU.
__global__ __launch_bounds__(512, 4) void stream_main(
    const float* __restrict__ prev, const unsigned short* __restrict__ u_all,
    const int* __restrict__ vor,
    const unsigned short* __restrict__ Wtgt, const unsigned short* __restrict__ Wtgb,
    const float* __restrict__ bg, float* __restrict__ out) {
    __shared__ __align__(16) unsigned char prvb[64 * 512];  // bf16 swizzled prev tile
    __shared__ __align__(16) unsigned char u_st[64 * 512];  // bf16 swizzled u tile

    const int tid = threadIdx.x;
    const int lane = tid & 63;
    const int wv = tid >> 6;
    const int ln15 = lane & 15;
    const int khi = lane >> 4;
    const int ln31 = lane & 31;
    const int cb = wv * 32;
    const int m0 = blockIdx.x * 64;

    // per-lane: val index of row (m0+lane), -1 if unmapped
    int vr = -1;
    if (m0 + lane < NR_AST) vr = vor[m0 + lane];

    // ---- u gathers: async DMA, 2 rows/instr, source-side swizzle (L3-resident) ----
#pragma unroll
    for (int i = 0; i < 4; ++i) {
        int r0 = wv * 8 + i * 2;
        int row = r0 + (lane >> 5);
        int vidx = __shfl(vr, row);
        int vsrc = vidx < 0 ? 0 : vidx;
        const unsigned short* src = u_all + (size_t)vsrc * AST_DIM + ((ln31 ^ (row & 7)) << 3);
        dma16(src, u_st + (r0 << 9));
    }
    // ---- prev staging: SEQUENTIAL rows; unmapped rows stream straight to out ----
#pragma unroll
    for (int i = 0; i < 8; ++i) {
        int r = wv * 8 + i;
        int g = m0 + r;
        if (g < NR_AST) {   // wave-uniform
            f32x4 v = __builtin_nontemporal_load((const f32x4*)(prev + (size_t)g * AST_DIM) + lane);
            int addr = (r << 9) + ((lane << 3) ^ ((r & 7) << 4));
            *(u64*)(prvb + addr) = pack4(v);
            if (__shfl(vr, r) < 0)   // unmapped: exact f32 copy (wave-uniform branch)
                __builtin_nontemporal_store(v, (f32x4*)(out + (size_t)g * AST_DIM) + lane);
        }
    }
    __syncthreads();   // drains DMA + packs; the ONLY barrier

    // ---- GEMM2: z_pre = prev @ Wg_top + u @ Wg_bot + bg ----
    const float b0 = bg[cb + ln15], b1 = bg[cb + 16 + ln15];
    f32x4 acc[4][2];
#pragma unroll
    for (int mt = 0; mt < 4; ++mt) {
        acc[mt][0] = f32x4{b0, b0, b0, b0};
        acc[mt][1] = f32x4{b1, b1, b1, b1};
    }
#pragma unroll
    for (int ks = 0; ks < 8; ++ks) {
        short8 a[4], bfr[2];
#pragma unroll
        for (int mt = 0; mt < 4; ++mt) {
            int row = mt * 16 + ln15;
            int addr = (row << 9) + (((ks << 6) + (khi << 4)) ^ ((row & 7) << 4));
            a[mt] = *(const short8*)(prvb + addr);
        }
#pragma unroll
        for (int nt = 0; nt < 2; ++nt)
            bfr[nt] = *(const short8*)(Wtgt + (cb + nt * 16 + ln15) * 256 + ks * 32 + khi * 8);
#pragma unroll
        for (int mt = 0; mt < 4; ++mt)
#pragma unroll
            for (int nt = 0; nt < 2; ++nt)
                acc[mt][nt] = __builtin_amdgcn_mfma_f32_16x16x32_bf16(a[mt], bfr[nt], acc[mt][nt], 0, 0, 0);
    }
#pragma unroll
    for (int ks = 0; ks < 8; ++ks) {
        short8 a[4], bfr[2];
#pragma unroll
        for (int mt = 0; mt < 4; ++mt) {
            int row = mt * 16 + ln15;
            int addr = (row << 9) + ((((ks << 2) + khi) ^ (row & 7)) << 4);
            a[mt] = *(const short8*)(u_st + addr);
        }
#pragma unroll
        for (int nt = 0; nt < 2; ++nt)
            bfr[nt] = *(const short8*)(Wtgb + (cb + nt * 16 + ln15) * 256 + ks * 32 + khi * 8);
#pragma unroll
        for (int mt = 0; mt < 4; ++mt)
#pragma unroll
            for (int nt = 0; nt < 2; ++nt)
                acc[mt][nt] = __builtin_amdgcn_mfma_f32_16x16x32_bf16(a[mt], bfr[nt], acc[mt][nt], 0, 0, 0);
    }

    // ---- epilogue: z = sigmoid, blend, sequential store (mapped rows only) ----
#pragma unroll
    for (int mt = 0; mt < 4; ++mt)
#pragma unroll
        for (int rr = 0; rr < 4; ++rr) {
            int row = mt * 16 + khi * 4 + rr;
            int g = m0 + row;
            int vrow = __shfl(vr, row);
            if (g < NR_AST && vrow >= 0) {
                float* orow = out + (size_t)g * AST_DIM;
#pragma unroll
                for (int nt = 0; nt < 2; ++nt) {
                    int col = cb + nt * 16 + ln15;
                    float z = fast_sigmoid(acc[mt][nt][rr]);
                    float pf = bf2f(*(const unsigned short*)(prvb + (row << 9) + ((col << 1) ^ ((row & 7) << 4))));
                    float uv = bf2f(*(const unsigned short*)(u_st + (row << 9) +
                                    ((((col >> 3) ^ (row & 7)) << 4) + ((col & 7) << 1))));
                    __builtin_nontemporal_store(fmaf(z, pf - uv, uv), orow + col);  // z*prev+(1-z)*u
                }
            }
        }
}

// ---------------- fallback path (ws too small): round-1 structure ----------------
__global__ void set_mask(const int* __restrict__ keys, unsigned char* __restrict__ mask) {
    int i = blockIdx.x * 256 + threadIdx.x;
    if (i < NR_MAP) mask[keys[i]] = 1;
}

__global__ void copy_unmapped(const float* __restrict__ prev,
                              const unsigned char* __restrict__ mask,
                              float* __restrict__ out) {
    const long long total = (long long)NR_AST * 64;
    for (long long i = (long long)blockIdx.x * blockDim.x + threadIdx.x; i < total;
         i += (long long)gridDim.x * blockDim.x) {
        int row = (int)(i >> 6);
        if (!mask[row]) {
            f32x4 v = __builtin_nontemporal_load((const f32x4*)prev + i);
            __builtin_nontemporal_store(v, (f32x4*)out + i);
        }
    }
}

__global__ __launch_bounds__(512, 4) void mixer_fused(
    const float* __restrict__ prev, const float* __restrict__ cfg,
    const int* __restrict__ keys, const int* __restrict__ vals,
    const unsigned short* __restrict__ Wtu, const unsigned short* __restrict__ Wtgt,
    const unsigned short* __restrict__ Wtgb, const float* __restrict__ bu,
    const float* __restrict__ bg, float* __restrict__ out) {
    __shared__ __align__(16) unsigned char ctx_lds[64 * 512];
    __shared__ __align__(16) unsigned char prv_lds[64 * 512];

    const int tid = threadIdx.x;
    const int lane = tid & 63;
    const int wave = tid >> 6;
    const int ln15 = lane & 15;
    const int khi = lane >> 4;
    const int cb = wave * 32;
    const int m0 = blockIdx.x * 64;

    const int kv = keys[m0 + lane];
    const int vv = vals[m0 + lane];

#pragma unroll 4
    for (int i = 0; i < 8; ++i) {
        int r = i * 8 + wave;
        f32x4 cv = *((const f32x4*)(cfg + (size_t)__shfl(vv, r) * AST_DIM) + lane);
        f32x4 pv = *((const f32x4*)(prev + (size_t)__shfl(kv, r) * AST_DIM) + lane);
        int addr = (r << 9) + ((lane << 3) ^ ((r & 7) << 4));
        *(u64*)(ctx_lds + addr) = pack4(cv);
        *(u64*)(prv_lds + addr) = pack4(pv);
    }
    __syncthreads();

    f32x4 acc[4][2];
    {
        float b0 = bu[cb + ln15], b1 = bu[cb + 16 + ln15];
        for (int mt = 0; mt < 4; ++mt) {
            acc[mt][0] = f32x4{b0, b0, b0, b0};
            acc[mt][1] = f32x4{b1, b1, b1, b1};
        }
    }
#pragma unroll
    for (int ks = 0; ks < 8; ++ks) {
        short8 a[4], b[2];
        for (int mt = 0; mt < 4; ++mt) {
            int row = mt * 16 + ln15;
            int addr = (row << 9) + (((ks << 6) + (khi << 4)) ^ ((row & 7) << 4));
            a[mt] = *(const short8*)(ctx_lds + addr);
        }
        for (int nt = 0; nt < 2; ++nt)
            b[nt] = *(const short8*)(Wtu + (cb + nt * 16 + ln15) * 256 + ks * 32 + khi * 8);
        for (int mt = 0; mt < 4; ++mt)
            for (int nt = 0; nt < 2; ++nt)
                acc[mt][nt] = __builtin_amdgcn_mfma_f32_16x16x32_bf16(a[mt], b[nt], acc[mt][nt], 0, 0, 0);
    }
    __syncthreads();
#pragma unroll
    for (int mt = 0; mt < 4; ++mt)
        for (int rr = 0; rr < 4; ++rr) {
            int row = mt * 16 + khi * 4 + rr;
            for (int nt = 0; nt < 2; ++nt) {
                int col = cb + nt * 16 + ln15;
                int addr = (row << 9) + ((col << 1) ^ ((row & 7) << 4));
                *(unsigned short*)(ctx_lds + addr) = f2bf(fast_tanh(acc[mt][nt][rr]));
            }
        }
    __syncthreads();
    {
        float b0 = bg[cb + ln15], b1 = bg[cb + 16 + ln15];
        for (int mt = 0; mt < 4; ++mt) {
            acc[mt][0] = f32x4{b0, b0, b0, b0};
            acc[mt][1] = f32x4{b1, b1, b1, b1};
        }
    }
#pragma unroll
    for (int ks = 0; ks < 8; ++ks) {
        short8 a[4], b[2];
        for (int mt = 0; mt < 4; ++mt) {
            int row = mt * 16 + ln15;
            int addr = (row << 9) + (((ks << 6) + (khi << 4)) ^ ((row & 7) << 4));
            a[mt] = *(const short8*)(prv_lds + addr);
        }
        for (int nt = 0; nt < 2; ++nt)
            b[nt] = *(const short8*)(Wtgt + (cb + nt * 16 + ln15) * 256 + ks * 32 + khi * 8);
        for (int mt = 0; mt < 4; ++mt)
            for (int nt = 0; nt < 2; ++nt)
                acc[mt][nt] = __builtin_amdgcn_mfma_f32_16x16x32_bf16(a[mt], b[nt], acc[mt][nt], 0, 0, 0);
    }
#pragma unroll
    for (int ks = 0; ks < 8; ++ks) {
        short8 a[4], b[2];
        for (int mt = 0; mt < 4; ++mt) {
            int row = mt * 16 + ln15;
            int addr = (row << 9) + (((ks << 6) + (khi << 4)) ^ ((row & 7) << 4));
            a[mt] = *(const short8*)(ctx_lds + addr);
        }
        for (int nt = 0; nt < 2; ++nt)
            b[nt] = *(const short8*)(Wtgb + (cb + nt * 16 + ln15) * 256 + ks * 32 + khi * 8);
        for (int mt = 0; mt < 4; ++mt)
            for (int nt = 0; nt < 2; ++nt)
                acc[mt][nt] = __builtin_amdgcn_mfma_f32_16x16x32_bf16(a[mt], b[nt], acc[mt][nt], 0, 0, 0);
    }
#pragma unroll
    for (int mt = 0; mt < 4; ++mt)
        for (int rr = 0; rr < 4; ++rr) {
            int row = mt * 16 + khi * 4 + rr;
            int key = __shfl(kv, row);
            float* orow = out + (size_t)key * AST_DIM;
            for (int nt = 0; nt < 2; ++nt) {
                int col = cb + nt * 16 + ln15;
                int ad = (row << 9) + ((col << 1) ^ ((row & 7) << 4));
                float z = fast_sigmoid(acc[mt][nt][rr]);
                float pf = bf2f(*(const unsigned short*)(prv_lds + ad));
                float uv = bf2f(*(const unsigned short*)(ctx_lds + ad));
                orow[col] = fmaf(z, pf - uv, uv);
            }
        }
}

extern "C" void kernel_launch(void* const* d_in, const int* in_sizes, int n_in,
                              void* d_out, int out_size, void* d_ws, size_t ws_size,
                              hipStream_t stream) {
    const float* prev = (const float*)d_in[0];
    const float* cfg = (const float*)d_in[1];
    const int* keys = (const int*)d_in[2];
    const int* vals = (const int*)d_in[3];
    const float* Wu = (const float*)d_in[4];
    const float* bu = (const float*)d_in[5];
    const float* Wg = (const float*)d_in[6];
    const float* bg = (const float*)d_in[7];
    float* out = (float*)d_out;

    // ws: [0,384K) wt | [1MB,+2MB) val_of_row | [4MB,+51.2MB) u_all
    unsigned short* wt = (unsigned short*)d_ws;
    int* vor = (int*)((char*)d_ws + (1u << 20));
    unsigned short* u_all = (unsigned short*)((char*)d_ws + (4u << 20));
    const size_t ws_needed = (size_t)(4u << 20) + (size_t)NR_CFG * AST_DIM * 2;  // ~55.4 MB

    convert_w<<<768, 256, 0, stream>>>(Wu, Wg, wt);
    if (ws_size >= ws_needed) {
        (void)hipMemsetAsync(vor, 0xFF, (size_t)NR_AST * 4, stream);   // -1
        build_vor<<<(NR_MAP + 255) / 256, 256, 0, stream>>>(keys, vals, vor);
        compute_u<<<(NR_CFG + 63) / 64, 512, 0, stream>>>(cfg, wt, bu, u_all);
        stream_main<<<NBLK_MAIN, 512, 0, stream>>>(prev, u_all, vor,
                                                   wt + 65536, wt + 2 * 65536, bg, out);
    } else {
        unsigned char* mask = (unsigned char*)d_ws + 3 * 65536 * 2;
        (void)hipMemsetAsync(mask, 0, NR_AST, stream);
        set_mask<<<(NR_MAP + 255) / 256, 256, 0, stream>>>(keys, mask);
        copy_unmapped<<<2048, 256, 0, stream>>>(prev, mask, out);
        mixer_fused<<<NR_MAP / 64, 512, 0, stream>>>(prev, cfg, keys, vals, wt, wt + 65536,
                                                     wt + 2 * 65536, bu, bg, out);
    }
}

// Round 11
// 410.452 us; speedup vs baseline: 1.6570x; 1.1103x over previous
//
#include <hip/hip_runtime.h>
#include <hip/hip_bf16.h>

#define AST_DIM 256
#define NR_AST 500000
#define NR_CFG 100000
#define NR_MAP 400000
#define NBLK_MAIN ((NR_AST + 63) / 64)   // 7813

typedef short short8 __attribute__((ext_vector_type(8)));
typedef float f32x4 __attribute__((ext_vector_type(4)));
typedef unsigned long long u64;
typedef unsigned int u32;

__device__ __forceinline__ unsigned short f2bf(float f) {
    u32 u = __float_as_uint(f);
    u += 0x7FFFu + ((u >> 16) & 1u);   // RNE
    return (unsigned short)(u >> 16);
}
__device__ __forceinline__ float bf2f(unsigned short s) {
    return __uint_as_float(((u32)s) << 16);
}
__device__ __forceinline__ u64 pack4(f32x4 v) {
    __hip_bfloat162 lo = __float22bfloat162_rn(float2{v.x, v.y});  // v_cvt_pk_bf16_f32
    __hip_bfloat162 hi = __float22bfloat162_rn(float2{v.z, v.w});
    return (u64)(*(u32*)&lo) | ((u64)(*(u32*)&hi) << 32);
}
__device__ __forceinline__ float fast_tanh(float x) {
    return 1.f - 2.f * __builtin_amdgcn_rcpf(__expf(2.f * x) + 1.f);
}
__device__ __forceinline__ float fast_sigmoid(float x) {
    return __builtin_amdgcn_rcpf(1.f + __expf(-x));
}
// async global->LDS DMA, 16B/lane: LDS dest = wave-uniform base + lane*16 (linear);
// global src is per-lane (enables source-side swizzling).
__device__ __forceinline__ void dma16(const void* g, void* l) {
    __builtin_amdgcn_global_load_lds((const __attribute__((address_space(1))) u32*)g,
                                     (__attribute__((address_space(3))) u32*)l, 16, 0, 0);
}

// W_update / W_gate (f32, [K][N]) -> bf16 transposed [N][K].
__global__ void convert_w(const float* __restrict__ Wu, const float* __restrict__ Wg,
                          unsigned short* __restrict__ wt) {
    int idx = blockIdx.x * 256 + threadIdx.x;
    if (idx >= 3 * 65536) return;
    int m = idx >> 16;
    int r = idx & 65535;
    int n = r >> 8;
    int k = r & 255;
    float v;
    if (m == 0)      v = Wu[k * 256 + n];
    else if (m == 1) v = Wg[k * 256 + n];
    else             v = Wg[(k + 256) * 256 + n];
    wt[idx] = f2bf(v);
}

// Invert the permutation: val_of_row[keys[m]] = vals[m]; elsewhere -1 (preset).
__global__ void build_vor(const int* __restrict__ keys, const int* __restrict__ vals,
                          int* __restrict__ vor) {
    int i = blockIdx.x * 256 + threadIdx.x;
    if (i < NR_MAP) vor[keys[i]] = vals[i];
}

// Pass A: u_all[c] = tanh(cfg[c] @ Wu + bu) for ALL 100K cfg rows (dense stream).
__global__ __launch_bounds__(512, 4) void compute_u(
    const float* __restrict__ cfg, const unsigned short* __restrict__ Wtu,
    const float* __restrict__ bu, unsigned short* __restrict__ u_all) {
    __shared__ __align__(16) unsigned char ctxb[64 * 512];

    const int tid = threadIdx.x;
    const int lane = tid & 63;
    const int wv = tid >> 6;
    const int ln15 = lane & 15;
    const int khi = lane >> 4;
    const int cb = wv * 32;
    const int m0 = blockIdx.x * 64;

    // issue ALL 8 row loads first (8 outstanding -> MLP), then pack
    f32x4 v[8];
#pragma unroll
    for (int i = 0; i < 8; ++i) {
        int g = m0 + wv * 8 + i;
        if (g >= NR_CFG) g = NR_CFG - 1;
        v[i] = *((const f32x4*)(cfg + (size_t)g * AST_DIM) + lane);
    }
    __builtin_amdgcn_sched_barrier(0);
#pragma unroll
    for (int i = 0; i < 8; ++i) {
        int r = wv * 8 + i;
        int addr = (r << 9) + ((lane << 3) ^ ((r & 7) << 4));
        *(u64*)(ctxb + addr) = pack4(v[i]);
    }
    __syncthreads();

    const float b0 = bu[cb + ln15], b1 = bu[cb + 16 + ln15];
    f32x4 acc[4][2];
#pragma unroll
    for (int mt = 0; mt < 4; ++mt) {
        acc[mt][0] = f32x4{b0, b0, b0, b0};
        acc[mt][1] = f32x4{b1, b1, b1, b1};
    }
#pragma unroll
    for (int ks = 0; ks < 8; ++ks) {
        short8 a[4], b[2];
#pragma unroll
        for (int mt = 0; mt < 4; ++mt) {
            int row = mt * 16 + ln15;
            int addr = (row << 9) + (((ks << 6) + (khi << 4)) ^ ((row & 7) << 4));
            a[mt] = *(const short8*)(ctxb + addr);
        }
#pragma unroll
        for (int nt = 0; nt < 2; ++nt)
            b[nt] = *(const short8*)(Wtu + (cb + nt * 16 + ln15) * 256 + ks * 32 + khi * 8);
#pragma unroll
        for (int mt = 0; mt < 4; ++mt)
#pragma unroll
            for (int nt = 0; nt < 2; ++nt)
                acc[mt][nt] = __builtin_amdgcn_mfma_f32_16x16x32_bf16(a[mt], b[nt], acc[mt][nt], 0, 0, 0);
    }
#pragma unroll
    for (int mt = 0; mt < 4; ++mt)
#pragma unroll
        for (int rr = 0; rr < 4; ++rr) {
            int row = mt * 16 + khi * 4 + rr;
            int g = m0 + row;
            if (g < NR_CFG) {
#pragma unroll
                for (int nt = 0; nt < 2; ++nt) {
                    int col = cb + nt * 16 + ln15;
                    u_all[(size_t)g * AST_DIM + col] = f2bf(fast_tanh(acc[mt][nt][rr]));
                }
            }
        }
}

// Main: iterate OUTPUT rows in order (prev read + out write both sequential);
// only u_all rows are gathered (51MB, L3-resident). Staging issues all 8 prev
// loads FIRST (pinned with sched_barrier) so 8 HBM requests fly concurrently —
// round 10 showed the compiler otherwise serializes them (VGPR=52, 2.0 TB/s).
__global__ __launch_bounds__(512, 4) void stream_main(
    const float* __restrict__ prev, const unsigned short* __restrict__ u_all,
    const int* __restrict__ vor,
    const unsigned short* __restrict__ Wtgt, const unsigned short* __restrict__ Wtgb,
    const float* __restrict__ bg, float* __restrict__ out) {
    __shared__ __align__(16) unsigned char prvb[64 * 512];  // bf16 swizzled prev tile
    __shared__ __align__(16) unsigned char u_st[64 * 512];  // bf16 swizzled u tile

    const int tid = threadIdx.x;
    const int lane = tid & 63;
    const int wv = tid >> 6;
    const int ln15 = lane & 15;
    const int khi = lane >> 4;
    const int ln31 = lane & 31;
    const int cb = wv * 32;
    const int m0 = blockIdx.x * 64;

    // per-lane: val index of row (m0+lane), -1 if unmapped
    int vr = -1;
    if (m0 + lane < NR_AST) vr = vor[m0 + lane];

    // ---- phase 1: issue 8 sequential prev-row loads (all outstanding) ----
    f32x4 v[8];
#pragma unroll
    for (int i = 0; i < 8; ++i) {
        int g = m0 + wv * 8 + i;
        if (g >= NR_AST) g = NR_AST - 1;   // clamp (last block); stores guarded below
        v[i] = __builtin_nontemporal_load((const f32x4*)(prev + (size_t)g * AST_DIM) + lane);
    }
    __builtin_amdgcn_sched_barrier(0);
    // ---- phase 2: issue u DMA gathers (newest in queue; stay in flight) ----
#pragma unroll
    for (int i = 0; i < 4; ++i) {
        int r0 = wv * 8 + i * 2;
        int row = r0 + (lane >> 5);
        int vidx = __shfl(vr, row);
        int vsrc = vidx < 0 ? 0 : vidx;
        const unsigned short* src = u_all + (size_t)vsrc * AST_DIM + ((ln31 ^ (row & 7)) << 3);
        dma16(src, u_st + (r0 << 9));
    }
    __builtin_amdgcn_sched_barrier(0);
    // ---- phase 3: pack prev -> swizzled LDS; unmapped rows stream to out ----
#pragma unroll
    for (int i = 0; i < 8; ++i) {
        int r = wv * 8 + i;
        int g = m0 + r;
        int addr = (r << 9) + ((lane << 3) ^ ((r & 7) << 4));
        *(u64*)(prvb + addr) = pack4(v[i]);
        if (g < NR_AST && __shfl(vr, r) < 0)   // unmapped: exact f32 copy (wave-uniform)
            __builtin_nontemporal_store(v[i], (f32x4*)(out + (size_t)g * AST_DIM) + lane);
    }
    __syncthreads();   // drains DMA + packs; the ONLY barrier

    // ---- GEMM2: z_pre = prev @ Wg_top + u @ Wg_bot + bg ----
    const float b0 = bg[cb + ln15], b1 = bg[cb + 16 + ln15];
    f32x4 acc[4][2];
#pragma unroll
    for (int mt = 0; mt < 4; ++mt) {
        acc[mt][0] = f32x4{b0, b0, b0, b0};
        acc[mt][1] = f32x4{b1, b1, b1, b1};
    }
#pragma unroll
    for (int ks = 0; ks < 8; ++ks) {
        short8 a[4], bfr[2];
#pragma unroll
        for (int mt = 0; mt < 4; ++mt) {
            int row = mt * 16 + ln15;
            int addr = (row << 9) + (((ks << 6) + (khi << 4)) ^ ((row & 7) << 4));
            a[mt] = *(const short8*)(prvb + addr);
        }
#pragma unroll
        for (int nt = 0; nt < 2; ++nt)
            bfr[nt] = *(const short8*)(Wtgt + (cb + nt * 16 + ln15) * 256 + ks * 32 + khi * 8);
#pragma unroll
        for (int mt = 0; mt < 4; ++mt)
#pragma unroll
            for (int nt = 0; nt < 2; ++nt)
                acc[mt][nt] = __builtin_amdgcn_mfma_f32_16x16x32_bf16(a[mt], bfr[nt], acc[mt][nt], 0, 0, 0);
    }
#pragma unroll
    for (int ks = 0; ks < 8; ++ks) {
        short8 a[4], bfr[2];
#pragma unroll
        for (int mt = 0; mt < 4; ++mt) {
            int row = mt * 16 + ln15;
            int addr = (row << 9) + ((((ks << 2) + khi) ^ (row & 7)) << 4);
            a[mt] = *(const short8*)(u_st + addr);
        }
#pragma unroll
        for (int nt = 0; nt < 2; ++nt)
            bfr[nt] = *(const short8*)(Wtgb + (cb + nt * 16 + ln15) * 256 + ks * 32 + khi * 8);
#pragma unroll
        for (int mt = 0; mt < 4; ++mt)
#pragma unroll
            for (int nt = 0; nt < 2; ++nt)
                acc[mt][nt] = __builtin_amdgcn_mfma_f32_16x16x32_bf16(a[mt], bfr[nt], acc[mt][nt], 0, 0, 0);
    }

    // ---- epilogue: z = sigmoid, blend, sequential store (mapped rows only) ----
#pragma unroll
    for (int mt = 0; mt < 4; ++mt)
#pragma unroll
        for (int rr = 0; rr < 4; ++rr) {
            int row = mt * 16 + khi * 4 + rr;
            int g = m0 + row;
            int vrow = __shfl(vr, row);
            if (g < NR_AST && vrow >= 0) {
                float* orow = out + (size_t)g * AST_DIM;
#pragma unroll
                for (int nt = 0; nt < 2; ++nt) {
                    int col = cb + nt * 16 + ln15;
                    float z = fast_sigmoid(acc[mt][nt][rr]);
                    float pf = bf2f(*(const unsigned short*)(prvb + (row << 9) + ((col << 1) ^ ((row & 7) << 4))));
                    float uv = bf2f(*(const unsigned short*)(u_st + (row << 9) +
                                    ((((col >> 3) ^ (row & 7)) << 4) + ((col & 7) << 1))));
                    __builtin_nontemporal_store(fmaf(z, pf - uv, uv), orow + col);  // z*prev+(1-z)*u
                }
            }
        }
}

// ---------------- fallback path (ws too small): round-1 structure ----------------
__global__ void set_mask(const int* __restrict__ keys, unsigned char* __restrict__ mask) {
    int i = blockIdx.x * 256 + threadIdx.x;
    if (i < NR_MAP) mask[keys[i]] = 1;
}

__global__ void copy_unmapped(const float* __restrict__ prev,
                              const unsigned char* __restrict__ mask,
                              float* __restrict__ out) {
    const long long total = (long long)NR_AST * 64;
    for (long long i = (long long)blockIdx.x * blockDim.x + threadIdx.x; i < total;
         i += (long long)gridDim.x * blockDim.x) {
        int row = (int)(i >> 6);
        if (!mask[row]) {
            f32x4 v = __builtin_nontemporal_load((const f32x4*)prev + i);
            __builtin_nontemporal_store(v, (f32x4*)out + i);
        }
    }
}

__global__ __launch_bounds__(512, 4) void mixer_fused(
    const float* __restrict__ prev, const float* __restrict__ cfg,
    const int* __restrict__ keys, const int* __restrict__ vals,
    const unsigned short* __restrict__ Wtu, const unsigned short* __restrict__ Wtgt,
    const unsigned short* __restrict__ Wtgb, const float* __restrict__ bu,
    const float* __restrict__ bg, float* __restrict__ out) {
    __shared__ __align__(16) unsigned char ctx_lds[64 * 512];
    __shared__ __align__(16) unsigned char prv_lds[64 * 512];

    const int tid = threadIdx.x;
    const int lane = tid & 63;
    const int wave = tid >> 6;
    const int ln15 = lane & 15;
    const int khi = lane >> 4;
    const int cb = wave * 32;
    const int m0 = blockIdx.x * 64;

    const int kv = keys[m0 + lane];
    const int vv = vals[m0 + lane];

#pragma unroll 4
    for (int i = 0; i < 8; ++i) {
        int r = i * 8 + wave;
        f32x4 cv = *((const f32x4*)(cfg + (size_t)__shfl(vv, r) * AST_DIM) + lane);
        f32x4 pv = *((const f32x4*)(prev + (size_t)__shfl(kv, r) * AST_DIM) + lane);
        int addr = (r << 9) + ((lane << 3) ^ ((r & 7) << 4));
        *(u64*)(ctx_lds + addr) = pack4(cv);
        *(u64*)(prv_lds + addr) = pack4(pv);
    }
    __syncthreads();

    f32x4 acc[4][2];
    {
        float b0 = bu[cb + ln15], b1 = bu[cb + 16 + ln15];
        for (int mt = 0; mt < 4; ++mt) {
            acc[mt][0] = f32x4{b0, b0, b0, b0};
            acc[mt][1] = f32x4{b1, b1, b1, b1};
        }
    }
#pragma unroll
    for (int ks = 0; ks < 8; ++ks) {
        short8 a[4], b[2];
        for (int mt = 0; mt < 4; ++mt) {
            int row = mt * 16 + ln15;
            int addr = (row << 9) + (((ks << 6) + (khi << 4)) ^ ((row & 7) << 4));
            a[mt] = *(const short8*)(ctx_lds + addr);
        }
        for (int nt = 0; nt < 2; ++nt)
            b[nt] = *(const short8*)(Wtu + (cb + nt * 16 + ln15) * 256 + ks * 32 + khi * 8);
        for (int mt = 0; mt < 4; ++mt)
            for (int nt = 0; nt < 2; ++nt)
                acc[mt][nt] = __builtin_amdgcn_mfma_f32_16x16x32_bf16(a[mt], b[nt], acc[mt][nt], 0, 0, 0);
    }
    __syncthreads();
#pragma unroll
    for (int mt = 0; mt < 4; ++mt)
        for (int rr = 0; rr < 4; ++rr) {
            int row = mt * 16 + khi * 4 + rr;
            for (int nt = 0; nt < 2; ++nt) {
                int col = cb + nt * 16 + ln15;
                int addr = (row << 9) + ((col << 1) ^ ((row & 7) << 4));
                *(unsigned short*)(ctx_lds + addr) = f2bf(fast_tanh(acc[mt][nt][rr]));
            }
        }
    __syncthreads();
    {
        float b0 = bg[cb + ln15], b1 = bg[cb + 16 + ln15];
        for (int mt = 0; mt < 4; ++mt) {
            acc[mt][0] = f32x4{b0, b0, b0, b0};
            acc[mt][1] = f32x4{b1, b1, b1, b1};
        }
    }
#pragma unroll
    for (int ks = 0; ks < 8; ++ks) {
        short8 a[4], b[2];
        for (int mt = 0; mt < 4; ++mt) {
            int row = mt * 16 + ln15;
            int addr = (row << 9) + (((ks << 6) + (khi << 4)) ^ ((row & 7) << 4));
            a[mt] = *(const short8*)(prv_lds + addr);
        }
        for (int nt = 0; nt < 2; ++nt)
            b[nt] = *(const short8*)(Wtgt + (cb + nt * 16 + ln15) * 256 + ks * 32 + khi * 8);
        for (int mt = 0; mt < 4; ++mt)
            for (int nt = 0; nt < 2; ++nt)
                acc[mt][nt] = __builtin_amdgcn_mfma_f32_16x16x32_bf16(a[mt], b[nt], acc[mt][nt], 0, 0, 0);
    }
#pragma unroll
    for (int ks = 0; ks < 8; ++ks) {
        short8 a[4], b[2];
        for (int mt = 0; mt < 4; ++mt) {
            int row = mt * 16 + ln15;
            int addr = (row << 9) + (((ks << 6) + (khi << 4)) ^ ((row & 7) << 4));
            a[mt] = *(const short8*)(ctx_lds + addr);
        }
        for (int nt = 0; nt < 2; ++nt)
            b[nt] = *(const short8*)(Wtgb + (cb + nt * 16 + ln15) * 256 + ks * 32 + khi * 8);
        for (int mt = 0; mt < 4; ++mt)
            for (int nt = 0; nt < 2; ++nt)
                acc[mt][nt] = __builtin_amdgcn_mfma_f32_16x16x32_bf16(a[mt], b[nt], acc[mt][nt], 0, 0, 0);
    }
#pragma unroll
    for (int mt = 0; mt < 4; ++mt)
        for (int rr = 0; rr < 4; ++rr) {
            int row = mt * 16 + khi * 4 + rr;
            int key = __shfl(kv, row);
            float* orow = out + (size_t)key * AST_DIM;
            for (int nt = 0; nt < 2; ++nt) {
                int col = cb + nt * 16 + ln15;
                int ad = (row << 9) + ((col << 1) ^ ((row & 7) << 4));
                float z = fast_sigmoid(acc[mt][nt][rr]);
                float pf = bf2f(*(const unsigned short*)(prv_lds + ad));
                float uv = bf2f(*(const unsigned short*)(ctx_lds + ad));
                orow[col] = fmaf(z, pf - uv, uv);
            }
        }
}

extern "C" void kernel_launch(void* const* d_in, const int* in_sizes, int n_in,
                              void* d_out, int out_size, void* d_ws, size_t ws_size,
                              hipStream_t stream) {
    const float* prev = (const float*)d_in[0];
    const float* cfg = (const float*)d_in[1];
    const int* keys = (const int*)d_in[2];
    const int* vals = (const int*)d_in[3];
    const float* Wu = (const float*)d_in[4];
    const float* bu = (const float*)d_in[5];
    const float* Wg = (const float*)d_in[6];
    const float* bg = (const float*)d_in[7];
    float* out = (float*)d_out;

    // ws: [0,384K) wt | [1MB,+2MB) val_of_row | [4MB,+51.2MB) u_all
    unsigned short* wt = (unsigned short*)d_ws;
    int* vor = (int*)((char*)d_ws + (1u << 20));
    unsigned short* u_all = (unsigned short*)((char*)d_ws + (4u << 20));
    const size_t ws_needed = (size_t)(4u << 20) + (size_t)NR_CFG * AST_DIM * 2;  // ~55.4 MB

    convert_w<<<768, 256, 0, stream>>>(Wu, Wg, wt);
    if (ws_size >= ws_needed) {
        (void)hipMemsetAsync(vor, 0xFF, (size_t)NR_AST * 4, stream);   // -1
        build_vor<<<(NR_MAP + 255) / 256, 256, 0, stream>>>(keys, vals, vor);
        compute_u<<<(NR_CFG + 63) / 64, 512, 0, stream>>>(cfg, wt, bu, u_all);
        stream_main<<<NBLK_MAIN, 512, 0, stream>>>(prev, u_all, vor,
                                                   wt + 65536, wt + 2 * 65536, bg, out);
    } else {
        unsigned char* mask = (unsigned char*)d_ws + 3 * 65536 * 2;
        (void)hipMemsetAsync(mask, 0, NR_AST, stream);
        set_mask<<<(NR_MAP + 255) / 256, 256, 0, stream>>>(keys, mask);
        copy_unmapped<<<2048, 256, 0, stream>>>(prev, mask, out);
        mixer_fused<<<NR_MAP / 64, 512, 0, stream>>>(prev, cfg, keys, vals, wt, wt + 65536,
                                                     wt + 2 * 65536, bu, bg, out);
    }
}